// Round 5
// baseline (4645.947 us; speedup 1.0000x reference)
//
#include <hip/hip_runtime.h>
#include <hip/hip_fp16.h>
#include <hip/hip_cooperative_groups.h>

namespace cg = cooperative_groups;

#define FD 128            // feature dim
#define NB 512            // blocks: 2/CU x 256 CU -- conservative co-residency
#define BT 256            // threads per block
#define NWAVES (NB * BT / 64)   // 2048
#define RPW 25            // rows per wave: 2048*25 = 51200 >= 50000
#define RPB 4             // fallback path: rows per block

// ---------------- CSR build ----------------

__global__ void zero_i32(int* __restrict__ p, int n) {
  int i = blockIdx.x * blockDim.x + threadIdx.x;
  if (i < n) p[i] = 0;
}

__global__ void hist_kernel(const int* __restrict__ rows, int* __restrict__ cnt, int nnz) {
  int i = blockIdx.x * blockDim.x + threadIdx.x;
  if (i < nnz) atomicAdd(&cnt[rows[i]], 1);
}

// coalesced 3-phase scan
__global__ void block_reduce(const int* __restrict__ cnt, int* __restrict__ bsum, int n) {
  __shared__ int sm[256];
  int i = blockIdx.x * 256 + threadIdx.x;
  sm[threadIdx.x] = (i < n) ? cnt[i] : 0;
  __syncthreads();
  for (int off = 128; off > 0; off >>= 1) {
    if (threadIdx.x < off) sm[threadIdx.x] += sm[threadIdx.x + off];
    __syncthreads();
  }
  if (threadIdx.x == 0) bsum[blockIdx.x] = sm[0];
}

__global__ void scan_bsum(const int* __restrict__ bsum, int* __restrict__ bpre, int nb) {
  __shared__ int sm[1024];
  const int tid = threadIdx.x;
  sm[tid] = (tid < nb) ? bsum[tid] : 0;
  __syncthreads();
  for (int off = 1; off < 1024; off <<= 1) {
    int t = (tid >= off) ? sm[tid - off] : 0;
    __syncthreads();
    sm[tid] += t;
    __syncthreads();
  }
  if (tid < nb) bpre[tid] = (tid == 0) ? 0 : sm[tid - 1];
}

__global__ void block_scan(const int* __restrict__ cnt, const int* __restrict__ bpre,
                           int* __restrict__ row_ptr, int n) {
  __shared__ int sm[256];
  const int tid = threadIdx.x;
  int i = blockIdx.x * 256 + tid;
  sm[tid] = (i < n) ? cnt[i] : 0;
  __syncthreads();
  for (int off = 1; off < 256; off <<= 1) {
    int t = (tid >= off) ? sm[tid - off] : 0;
    __syncthreads();
    sm[tid] += t;
    __syncthreads();
  }
  if (i < n) row_ptr[i + 1] = sm[tid] + bpre[blockIdx.x];
  if (i == 0) row_ptr[0] = 0;
}

__global__ void copy_i32(const int* __restrict__ src, int* __restrict__ dst, int n) {
  int i = blockIdx.x * blockDim.x + threadIdx.x;
  if (i < n) dst[i] = src[i];
}

__global__ void scatter_kernel(const int* __restrict__ rows, const int* __restrict__ cols,
                               const float* __restrict__ vals, int* __restrict__ fill,
                               int* __restrict__ cols_s, float* __restrict__ vals_s, int nnz) {
  int i = blockIdx.x * blockDim.x + threadIdx.x;
  if (i < nnz) {
    int r = rows[i];
    int pos = atomicAdd(&fill[r], 1);
    cols_s[pos] = cols[i];
    vals_s[pos] = vals[i];
  }
}

__global__ void f32_to_f16(const float* __restrict__ src, __half* __restrict__ dst, int n4) {
  int i = blockIdx.x * blockDim.x + threadIdx.x;
  if (i < n4) {
    float4 v = ((const float4*)src)[i];
    __half2* d = (__half2*)dst + 2 * (size_t)i;
    d[0] = __floats2half2_rn(v.x, v.y);
    d[1] = __floats2half2_rn(v.z, v.w);
  }
}

// ---------------- shared gather ----------------
// One wave per row; lane owns __half2 (2 features) -> 128 features; 256B/edge.

__device__ __forceinline__ float2 gather_h(const int* __restrict__ rp,
                                           const int* __restrict__ cols,
                                           const float* __restrict__ vals,
                                           const __half* __restrict__ T,
                                           int r, int lane) {
  int e = rp[r];
  const int end = rp[r + 1];
  float2 s0 = make_float2(0.f, 0.f);
  float2 s1 = make_float2(0.f, 0.f);
  for (; e + 3 < end; e += 4) {
    int c0 = cols[e + 0], c1 = cols[e + 1], c2 = cols[e + 2], c3 = cols[e + 3];
    float v0 = vals[e + 0], v1 = vals[e + 1], v2 = vals[e + 2], v3 = vals[e + 3];
    float2 x0 = __half22float2(((const __half2*)(T + (size_t)c0 * FD))[lane]);
    float2 x1 = __half22float2(((const __half2*)(T + (size_t)c1 * FD))[lane]);
    float2 x2 = __half22float2(((const __half2*)(T + (size_t)c2 * FD))[lane]);
    float2 x3 = __half22float2(((const __half2*)(T + (size_t)c3 * FD))[lane]);
    s0.x = fmaf(v0, x0.x, s0.x); s0.y = fmaf(v0, x0.y, s0.y);
    s1.x = fmaf(v1, x1.x, s1.x); s1.y = fmaf(v1, x1.y, s1.y);
    s0.x = fmaf(v2, x2.x, s0.x); s0.y = fmaf(v2, x2.y, s0.y);
    s1.x = fmaf(v3, x3.x, s1.x); s1.y = fmaf(v3, x3.y, s1.y);
  }
  for (; e < end; ++e) {
    float v = vals[e];
    float2 x = __half22float2(((const __half2*)(T + (size_t)cols[e] * FD))[lane]);
    s0.x = fmaf(v, x.x, s0.x); s0.y = fmaf(v, x.y, s0.y);
  }
  return make_float2(s0.x + s1.x, s0.y + s1.y);
}

// ---------------- fused Chebyshev (cooperative) ----------------

__global__ __launch_bounds__(BT, 2) void cheb_coop(
    const int* __restrict__ rp, const int* __restrict__ cols, const float* __restrict__ vals,
    const float* __restrict__ X, __half* bufA, __half* bufB,
    float* __restrict__ out, const float* __restrict__ coeffs, int n, int M) {
  cg::grid_group grid = cg::this_grid();
  const int tid = blockIdx.x * blockDim.x + threadIdx.x;
  const int lane = threadIdx.x & 63;
  const int wave = tid >> 6;
  const int r0 = wave * RPW;

  // ---- phase 0: X -> fp16 into bufB ----
  const int n4 = n * FD / 4;
  const int nt = gridDim.x * blockDim.x;
  for (int i = tid; i < n4; i += nt) {
    float4 v = ((const float4*)X)[i];
    __half2* d = (__half2*)bufB + 2 * (size_t)i;
    d[0] = __floats2half2_rn(v.x, v.y);
    d[1] = __floats2half2_rn(v.z, v.w);
  }

  // own-row state in registers for the whole recurrence
  float2 acc[RPW];        // fp32 accumulator
  __half2 prevp[RPW];     // T_{k-2}[r]
  __half2 curp[RPW];      // T_{k-1}[r]
  const float c0 = coeffs[0], c1 = coeffs[1];
#pragma unroll
  for (int j = 0; j < RPW; ++j) {
    int r = r0 + j;
    acc[j] = make_float2(0.f, 0.f);
    curp[j] = __floats2half2_rn(0.f, 0.f);
    prevp[j] = __floats2half2_rn(0.f, 0.f);
    if (r < n) {
      float2 x = ((const float2*)(X + (size_t)r * FD))[lane];
      acc[j] = make_float2(c0 * x.x, c0 * x.y);
      prevp[j] = __floats2half2_rn(x.x, x.y);   // T0 in fp16 (matches bufB view)
    }
  }
  grid.sync();

  // ---- k = 1: T1 = L @ X(fp16) -> bufA ----
#pragma unroll
  for (int j = 0; j < RPW; ++j) {
    int r = r0 + j;
    if (r >= n) continue;
    float2 s = gather_h(rp, cols, vals, bufB, r, lane);
    acc[j].x = fmaf(c1, s.x, acc[j].x);
    acc[j].y = fmaf(c1, s.y, acc[j].y);
    curp[j] = __floats2half2_rn(s.x, s.y);
    ((__half2*)(bufA + (size_t)r * FD))[lane] = curp[j];
  }
  grid.sync();

  // ---- k = 2..M-1 ----
  for (int k = 2; k < M; ++k) {
    const __half* src = (k & 1) ? bufB : bufA;
    __half* dst = (k & 1) ? bufA : bufB;
    const float ck = coeffs[k];
    const bool last = (k == M - 1);
#pragma unroll
    for (int j = 0; j < RPW; ++j) {
      int r = r0 + j;
      if (r >= n) continue;
      float2 s = gather_h(rp, cols, vals, src, r, lane);
      float2 p = __half22float2(prevp[j]);
      float2 t;
      t.x = fmaf(2.f, s.x, -p.x);
      t.y = fmaf(2.f, s.y, -p.y);
      __half2 tp = __floats2half2_rn(t.x, t.y);
      if (!last) ((__half2*)(dst + (size_t)r * FD))[lane] = tp;
      acc[j].x = fmaf(ck, t.x, acc[j].x);
      acc[j].y = fmaf(ck, t.y, acc[j].y);
      prevp[j] = curp[j];
      curp[j] = tp;
    }
    if (!last) grid.sync();
  }

  // ---- epilogue ----
#pragma unroll
  for (int j = 0; j < RPW; ++j) {
    int r = r0 + j;
    if (r < n) ((float2*)(out + (size_t)r * FD))[lane] = acc[j];
  }
}

// ---------------- fallback path (R3 structure, proven 1619 us) ----------------

__global__ __launch_bounds__(256) void spmm_first(
    const int* __restrict__ rp, const int* __restrict__ cols, const float* __restrict__ vals,
    const __half* __restrict__ Xh, const float* __restrict__ X,
    __half* __restrict__ T1, float* __restrict__ out,
    const float* __restrict__ coeffs, int n) {
  const int lane = threadIdx.x & 63;
  const int r = blockIdx.x * RPB + (threadIdx.x >> 6);
  if (r >= n) return;
  float2 sum = gather_h(rp, cols, vals, Xh, r, lane);
  ((__half2*)(T1 + (size_t)r * FD))[lane] = __floats2half2_rn(sum.x, sum.y);
  const float c0 = coeffs[0], c1 = coeffs[1];
  float2 x = ((const float2*)(X + (size_t)r * FD))[lane];
  float2 a;
  a.x = fmaf(c1, sum.x, c0 * x.x);
  a.y = fmaf(c1, sum.y, c0 * x.y);
  ((float2*)(out + (size_t)r * FD))[lane] = a;
}

__global__ __launch_bounds__(256) void spmm_step(
    const int* __restrict__ rp, const int* __restrict__ cols, const float* __restrict__ vals,
    const __half* __restrict__ src, const __half* prev, __half* dst,
    float* __restrict__ out, const float* __restrict__ coeffs, int k, int n) {
  const int lane = threadIdx.x & 63;
  const int r = blockIdx.x * RPB + (threadIdx.x >> 6);
  if (r >= n) return;
  float2 sum = gather_h(rp, cols, vals, src, r, lane);
  const float ck = coeffs[k];
  float2 p = __half22float2(((const __half2*)(prev + (size_t)r * FD))[lane]);
  float2 t;
  t.x = fmaf(2.f, sum.x, -p.x);
  t.y = fmaf(2.f, sum.y, -p.y);
  ((__half2*)(dst + (size_t)r * FD))[lane] = __floats2half2_rn(t.x, t.y);
  float2 a = ((float2*)(out + (size_t)r * FD))[lane];
  a.x = fmaf(ck, t.x, a.x);
  a.y = fmaf(ck, t.y, a.y);
  ((float2*)(out + (size_t)r * FD))[lane] = a;
}

// ---------------- launch ----------------

extern "C" void kernel_launch(void* const* d_in, const int* in_sizes, int n_in,
                              void* d_out, int out_size, void* d_ws, size_t ws_size,
                              hipStream_t stream) {
  const int* rows = (const int*)d_in[0];
  const int* cols = (const int*)d_in[1];
  const float* vals = (const float*)d_in[2];
  const float* X = (const float*)d_in[3];
  const float* coeffs = (const float*)d_in[4];
  float* out = (float*)d_out;

  const int nnz = in_sizes[0];
  const int n = in_sizes[3] / FD;
  const int M = in_sizes[4];

  auto align_up = [](size_t x) { return (x + 255) & ~(size_t)255; };
  char* w = (char*)d_ws;
  size_t off = 0;
  int* row_ptr = (int*)(w + off); off = align_up(off + (size_t)(n + 1) * 4);
  int* row_fill = (int*)(w + off); off = align_up(off + (size_t)n * 4);
  int* bsum = (int*)(w + off); off = align_up(off + 1024 * 4);
  int* bpre = (int*)(w + off); off = align_up(off + 1024 * 4);
  int* cols_s = (int*)(w + off); off = align_up(off + (size_t)nnz * 4);
  float* vals_s = (float*)(w + off); off = align_up(off + (size_t)nnz * 4);
  __half* bufA = (__half*)(w + off); off = align_up(off + (size_t)n * FD * 2);
  __half* bufB = (__half*)(w + off); off = align_up(off + (size_t)n * FD * 2);
  (void)ws_size;

  const int B = 256;
  const int gN = (n + B - 1) / B;
  const int gE = (nnz + B - 1) / B;

  // CSR build
  zero_i32<<<gN, B, 0, stream>>>(row_fill, n);
  hist_kernel<<<gE, B, 0, stream>>>(rows, row_fill, nnz);
  block_reduce<<<gN, B, 0, stream>>>(row_fill, bsum, n);
  scan_bsum<<<1, 1024, 0, stream>>>(bsum, bpre, gN);
  block_scan<<<gN, B, 0, stream>>>(row_fill, bpre, row_ptr, n);
  copy_i32<<<gN, B, 0, stream>>>(row_ptr, row_fill, n);
  scatter_kernel<<<gE, B, 0, stream>>>(rows, cols, vals, row_fill, cols_s, vals_s, nnz);

  // try fused cooperative path
  int n_ = n, M_ = M;
  const int* rp_ = row_ptr; const int* cs_ = cols_s; const float* vs_ = vals_s;
  const float* X_ = X; const float* cf_ = coeffs;
  __half* bA_ = bufA; __half* bB_ = bufB; float* out_ = out;
  void* args[] = {&rp_, &cs_, &vs_, &X_, &bA_, &bB_, &out_, &cf_, &n_, &M_};
  hipError_t e = hipLaunchCooperativeKernel((void*)cheb_coop, dim3(NB), dim3(BT),
                                            args, 0, stream);
  if (e != hipSuccess) {
    (void)hipGetLastError();  // clear sticky error; fall back to multi-launch path
    const int gS = (n + RPB - 1) / RPB;
    const int n4 = n * FD / 4;
    const int gC = (n4 + B - 1) / B;
    f32_to_f16<<<gC, B, 0, stream>>>(X, bufB, n4);  // Xh in bufB
    spmm_first<<<gS, B, 0, stream>>>(row_ptr, cols_s, vals_s, bufB, X, bufA, out, coeffs, n);
    // k=2: src=bufA(T1), prev=Xh(bufB) -- but dst would overwrite bufB which is prev.
    // Safe: same element read (prev) then written (dst) by the same thread only.
    if (M > 2)
      spmm_step<<<gS, B, 0, stream>>>(row_ptr, cols_s, vals_s, bufA, bufB, bufB, out,
                                      coeffs, 2, n);
    for (int k = 3; k < M; ++k) {
      __half* src = (k & 1) ? bufB : bufA;
      __half* pd  = (k & 1) ? bufA : bufB;
      spmm_step<<<gS, B, 0, stream>>>(row_ptr, cols_s, vals_s, src, pd, pd, out,
                                      coeffs, k, n);
    }
  }
}

// Round 6
// 1210.608 us; speedup vs baseline: 3.8377x; 3.8377x over previous
//
#include <hip/hip_runtime.h>
#include <hip/hip_fp16.h>

#define FD 128          // feature dim
#define RPB 4           // rows (waves) per block; block = 256 threads

// ---------------- CSR build ----------------

__global__ void zero_i32(int* __restrict__ p, int n) {
  int i = blockIdx.x * blockDim.x + threadIdx.x;
  if (i < n) p[i] = 0;
}

__global__ void hist_kernel(const int* __restrict__ rows, int* __restrict__ cnt, int nnz) {
  int i = blockIdx.x * blockDim.x + threadIdx.x;
  if (i < nnz) atomicAdd(&cnt[rows[i]], 1);
}

// coalesced 3-phase scan (R3's thread-serial scan was uncoalesced: 79us on 1 CU)
__global__ void block_reduce(const int* __restrict__ cnt, int* __restrict__ bsum, int n) {
  __shared__ int sm[256];
  int i = blockIdx.x * 256 + threadIdx.x;
  sm[threadIdx.x] = (i < n) ? cnt[i] : 0;
  __syncthreads();
  for (int off = 128; off > 0; off >>= 1) {
    if (threadIdx.x < off) sm[threadIdx.x] += sm[threadIdx.x + off];
    __syncthreads();
  }
  if (threadIdx.x == 0) bsum[blockIdx.x] = sm[0];
}

__global__ void scan_bsum(const int* __restrict__ bsum, int* __restrict__ bpre, int nb) {
  __shared__ int sm[1024];
  const int tid = threadIdx.x;
  sm[tid] = (tid < nb) ? bsum[tid] : 0;
  __syncthreads();
  for (int off = 1; off < 1024; off <<= 1) {
    int t = (tid >= off) ? sm[tid - off] : 0;
    __syncthreads();
    sm[tid] += t;
    __syncthreads();
  }
  if (tid < nb) bpre[tid] = (tid == 0) ? 0 : sm[tid - 1];
}

__global__ void block_scan(const int* __restrict__ cnt, const int* __restrict__ bpre,
                           int* __restrict__ row_ptr, int n) {
  __shared__ int sm[256];
  const int tid = threadIdx.x;
  int i = blockIdx.x * 256 + tid;
  sm[tid] = (i < n) ? cnt[i] : 0;
  __syncthreads();
  for (int off = 1; off < 256; off <<= 1) {
    int t = (tid >= off) ? sm[tid - off] : 0;
    __syncthreads();
    sm[tid] += t;
    __syncthreads();
  }
  if (i < n) row_ptr[i + 1] = sm[tid] + bpre[blockIdx.x];
  if (i == 0) row_ptr[0] = 0;
}

__global__ void copy_i32(const int* __restrict__ src, int* __restrict__ dst, int n) {
  int i = blockIdx.x * blockDim.x + threadIdx.x;
  if (i < n) dst[i] = src[i];
}

__global__ void scatter_kernel(const int* __restrict__ rows, const int* __restrict__ cols,
                               const float* __restrict__ vals, int* __restrict__ fill,
                               int* __restrict__ cols_s, float* __restrict__ vals_s, int nnz) {
  int i = blockIdx.x * blockDim.x + threadIdx.x;
  if (i < nnz) {
    int r = rows[i];
    int pos = atomicAdd(&fill[r], 1);
    cols_s[pos] = cols[i];
    vals_s[pos] = vals[i];
  }
}

__global__ void f32_to_f16(const float* __restrict__ src, __half* __restrict__ dst, int n4) {
  int i = blockIdx.x * blockDim.x + threadIdx.x;
  if (i < n4) {
    float4 v = ((const float4*)src)[i];
    __half2* d = (__half2*)dst + 2 * (size_t)i;
    d[0] = __floats2half2_rn(v.x, v.y);
    d[1] = __floats2half2_rn(v.z, v.w);
  }
}

// b_{M-1} = c_{M-1} * X (elementwise, fp16)
__global__ void clen_first(const __half2* __restrict__ Xh, __half2* __restrict__ b,
                           const float* __restrict__ coeffs, int kidx, int n2) {
  int i = blockIdx.x * blockDim.x + threadIdx.x;
  if (i < n2) {
    const float c = coeffs[kidx];
    float2 x = __half22float2(Xh[i]);
    b[i] = __floats2half2_rn(c * x.x, c * x.y);
  }
}

// ---------------- gather: one wave per row, lane = __half2 (2 features) ----------------
// 256B coalesced sweep per edge; cols/vals are wave-uniform -> scalar loads.

__device__ __forceinline__ float2 gather_h(const int* __restrict__ rp,
                                           const int* __restrict__ cols,
                                           const float* __restrict__ vals,
                                           const __half* __restrict__ T,
                                           int r, int lane) {
  int e = rp[r];
  const int end = rp[r + 1];
  float2 s0 = make_float2(0.f, 0.f);
  float2 s1 = make_float2(0.f, 0.f);
  float2 s2 = make_float2(0.f, 0.f);
  float2 s3 = make_float2(0.f, 0.f);
  for (; e + 7 < end; e += 8) {
    int c0 = cols[e + 0], c1 = cols[e + 1], c2 = cols[e + 2], c3 = cols[e + 3];
    int c4 = cols[e + 4], c5 = cols[e + 5], c6 = cols[e + 6], c7 = cols[e + 7];
    float v0 = vals[e + 0], v1 = vals[e + 1], v2 = vals[e + 2], v3 = vals[e + 3];
    float v4 = vals[e + 4], v5 = vals[e + 5], v6 = vals[e + 6], v7 = vals[e + 7];
    float2 x0 = __half22float2(((const __half2*)(T + (size_t)c0 * FD))[lane]);
    float2 x1 = __half22float2(((const __half2*)(T + (size_t)c1 * FD))[lane]);
    float2 x2 = __half22float2(((const __half2*)(T + (size_t)c2 * FD))[lane]);
    float2 x3 = __half22float2(((const __half2*)(T + (size_t)c3 * FD))[lane]);
    float2 x4 = __half22float2(((const __half2*)(T + (size_t)c4 * FD))[lane]);
    float2 x5 = __half22float2(((const __half2*)(T + (size_t)c5 * FD))[lane]);
    float2 x6 = __half22float2(((const __half2*)(T + (size_t)c6 * FD))[lane]);
    float2 x7 = __half22float2(((const __half2*)(T + (size_t)c7 * FD))[lane]);
    s0.x = fmaf(v0, x0.x, s0.x); s0.y = fmaf(v0, x0.y, s0.y);
    s1.x = fmaf(v1, x1.x, s1.x); s1.y = fmaf(v1, x1.y, s1.y);
    s2.x = fmaf(v2, x2.x, s2.x); s2.y = fmaf(v2, x2.y, s2.y);
    s3.x = fmaf(v3, x3.x, s3.x); s3.y = fmaf(v3, x3.y, s3.y);
    s0.x = fmaf(v4, x4.x, s0.x); s0.y = fmaf(v4, x4.y, s0.y);
    s1.x = fmaf(v5, x5.x, s1.x); s1.y = fmaf(v5, x5.y, s1.y);
    s2.x = fmaf(v6, x6.x, s2.x); s2.y = fmaf(v6, x6.y, s2.y);
    s3.x = fmaf(v7, x7.x, s3.x); s3.y = fmaf(v7, x7.y, s3.y);
  }
  for (; e + 1 < end; e += 2) {
    int c0 = cols[e + 0], c1 = cols[e + 1];
    float v0 = vals[e + 0], v1 = vals[e + 1];
    float2 x0 = __half22float2(((const __half2*)(T + (size_t)c0 * FD))[lane]);
    float2 x1 = __half22float2(((const __half2*)(T + (size_t)c1 * FD))[lane]);
    s0.x = fmaf(v0, x0.x, s0.x); s0.y = fmaf(v0, x0.y, s0.y);
    s1.x = fmaf(v1, x1.x, s1.x); s1.y = fmaf(v1, x1.y, s1.y);
  }
  if (e < end) {
    float v = vals[e];
    float2 x = __half22float2(((const __half2*)(T + (size_t)cols[e] * FD))[lane]);
    s0.x = fmaf(v, x.x, s0.x); s0.y = fmaf(v, x.y, s0.y);
  }
  return make_float2((s0.x + s1.x) + (s2.x + s3.x), (s0.y + s1.y) + (s2.y + s3.y));
}

// ---------------- Clenshaw steps ----------------
// b_k = 2*(L @ b_{k+1}) - b_{k+2} + c_k * X   (fp16 state, fp32 math)
// pd holds b_{k+2} and receives b_k (same element, same thread -> safe in-place).

__global__ __launch_bounds__(256) void clen_step(
    const int* __restrict__ rp, const int* __restrict__ cols, const float* __restrict__ vals,
    const __half* __restrict__ src, const __half* __restrict__ Xh, __half* pd,
    const float* __restrict__ coeffs, int k, int has_p, int n) {
  const int lane = threadIdx.x & 63;
  const int r = blockIdx.x * RPB + (threadIdx.x >> 6);
  if (r >= n) return;
  float2 s = gather_h(rp, cols, vals, src, r, lane);
  const float ck = coeffs[k];
  float2 x = __half22float2(((const __half2*)(Xh + (size_t)r * FD))[lane]);
  float2 p = make_float2(0.f, 0.f);
  if (has_p) p = __half22float2(((const __half2*)(pd + (size_t)r * FD))[lane]);
  float2 t;
  t.x = fmaf(2.f, s.x, fmaf(ck, x.x, -p.x));
  t.y = fmaf(2.f, s.y, fmaf(ck, x.y, -p.y));
  ((__half2*)(pd + (size_t)r * FD))[lane] = __floats2half2_rn(t.x, t.y);
}

// out = c0*X + L @ b1 - b2   (fp32 X and output)
__global__ __launch_bounds__(256) void clen_final(
    const int* __restrict__ rp, const int* __restrict__ cols, const float* __restrict__ vals,
    const __half* __restrict__ b1, const __half* __restrict__ b2,
    const float* __restrict__ X, float* __restrict__ out,
    const float* __restrict__ coeffs, int n) {
  const int lane = threadIdx.x & 63;
  const int r = blockIdx.x * RPB + (threadIdx.x >> 6);
  if (r >= n) return;
  float2 s = gather_h(rp, cols, vals, b1, r, lane);
  float2 p = __half22float2(((const __half2*)(b2 + (size_t)r * FD))[lane]);
  float2 x = ((const float2*)(X + (size_t)r * FD))[lane];
  const float c0 = coeffs[0];
  float2 o;
  o.x = fmaf(c0, x.x, s.x - p.x);
  o.y = fmaf(c0, x.y, s.y - p.y);
  ((float2*)(out + (size_t)r * FD))[lane] = o;
}

// ---------------- launch ----------------

extern "C" void kernel_launch(void* const* d_in, const int* in_sizes, int n_in,
                              void* d_out, int out_size, void* d_ws, size_t ws_size,
                              hipStream_t stream) {
  const int* rows = (const int*)d_in[0];
  const int* cols = (const int*)d_in[1];
  const float* vals = (const float*)d_in[2];
  const float* X = (const float*)d_in[3];
  const float* coeffs = (const float*)d_in[4];
  float* out = (float*)d_out;

  const int nnz = in_sizes[0];
  const int n = in_sizes[3] / FD;
  const int M = in_sizes[4];

  auto align_up = [](size_t x) { return (x + 255) & ~(size_t)255; };
  char* w = (char*)d_ws;
  size_t off = 0;
  int* row_ptr = (int*)(w + off); off = align_up(off + (size_t)(n + 1) * 4);
  int* row_fill = (int*)(w + off); off = align_up(off + (size_t)n * 4);
  int* bsum = (int*)(w + off); off = align_up(off + 1024 * 4);
  int* bpre = (int*)(w + off); off = align_up(off + 1024 * 4);
  int* cols_s = (int*)(w + off); off = align_up(off + (size_t)nnz * 4);
  float* vals_s = (float*)(w + off); off = align_up(off + (size_t)nnz * 4);
  __half* Xh = (__half*)(w + off); off = align_up(off + (size_t)n * FD * 2);
  __half* buf0 = (__half*)(w + off); off = align_up(off + (size_t)n * FD * 2);
  __half* buf1 = (__half*)(w + off); off = align_up(off + (size_t)n * FD * 2);
  __half* bufs[2] = {buf0, buf1};
  (void)ws_size;

  const int B = 256;
  const int gN = (n + B - 1) / B;
  const int gE = (nnz + B - 1) / B;
  const int gS = (n + RPB - 1) / RPB;
  const int n4 = n * FD / 4;
  const int gC = (n4 + B - 1) / B;
  const int n2 = n * FD / 2;
  const int gH = (n2 + B - 1) / B;

  // CSR build
  zero_i32<<<gN, B, 0, stream>>>(row_fill, n);
  hist_kernel<<<gE, B, 0, stream>>>(rows, row_fill, nnz);
  block_reduce<<<gN, B, 0, stream>>>(row_fill, bsum, n);
  scan_bsum<<<1, 1024, 0, stream>>>(bsum, bpre, gN);
  block_scan<<<gN, B, 0, stream>>>(row_fill, bpre, row_ptr, n);
  copy_i32<<<gN, B, 0, stream>>>(row_ptr, row_fill, n);
  scatter_kernel<<<gE, B, 0, stream>>>(rows, cols, vals, row_fill, cols_s, vals_s, nnz);
  f32_to_f16<<<gC, B, 0, stream>>>(X, Xh, n4);

  // Clenshaw: b_{M-1} = c_{M-1} X ; b_k = 2 L b_{k+1} - b_{k+2} + c_k X (k = M-2..1)
  // out = c0 X + L b1 - b2.  b_j lives in bufs[j & 1]; in-place b_k over b_{k+2}.
  clen_first<<<gH, B, 0, stream>>>((const __half2*)Xh, (__half2*)bufs[(M - 1) & 1],
                                   coeffs, M - 1, n2);
  for (int k = M - 2; k >= 1; --k) {
    clen_step<<<gS, B, 0, stream>>>(row_ptr, cols_s, vals_s,
                                    bufs[(k + 1) & 1], Xh, bufs[k & 1],
                                    coeffs, k, (k < M - 2) ? 1 : 0, n);
  }
  clen_final<<<gS, B, 0, stream>>>(row_ptr, cols_s, vals_s, bufs[1], bufs[0],
                                   X, out, coeffs, n);
}

// Round 7
// 1149.283 us; speedup vs baseline: 4.0425x; 1.0534x over previous
//
#include <hip/hip_runtime.h>
#include <hip/hip_fp16.h>

#define FD 128          // feature dim
#define RPB 4           // rows (waves) per block; block = 256 threads

// ---------------- CSR build ----------------

__global__ void zero_i32(int* __restrict__ p, int n) {
  int i = blockIdx.x * blockDim.x + threadIdx.x;
  if (i < n) p[i] = 0;
}

__global__ void hist_kernel(const int* __restrict__ rows, int* __restrict__ cnt, int nnz) {
  int i = blockIdx.x * blockDim.x + threadIdx.x;
  if (i < nnz) atomicAdd(&cnt[rows[i]], 1);
}

// coalesced 3-phase scan
__global__ void block_reduce(const int* __restrict__ cnt, int* __restrict__ bsum, int n) {
  __shared__ int sm[256];
  int i = blockIdx.x * 256 + threadIdx.x;
  sm[threadIdx.x] = (i < n) ? cnt[i] : 0;
  __syncthreads();
  for (int off = 128; off > 0; off >>= 1) {
    if (threadIdx.x < off) sm[threadIdx.x] += sm[threadIdx.x + off];
    __syncthreads();
  }
  if (threadIdx.x == 0) bsum[blockIdx.x] = sm[0];
}

__global__ void scan_bsum(const int* __restrict__ bsum, int* __restrict__ bpre, int nb) {
  __shared__ int sm[1024];
  const int tid = threadIdx.x;
  sm[tid] = (tid < nb) ? bsum[tid] : 0;
  __syncthreads();
  for (int off = 1; off < 1024; off <<= 1) {
    int t = (tid >= off) ? sm[tid - off] : 0;
    __syncthreads();
    sm[tid] += t;
    __syncthreads();
  }
  if (tid < nb) bpre[tid] = (tid == 0) ? 0 : sm[tid - 1];
}

__global__ void block_scan(const int* __restrict__ cnt, const int* __restrict__ bpre,
                           int* __restrict__ row_ptr, int n) {
  __shared__ int sm[256];
  const int tid = threadIdx.x;
  int i = blockIdx.x * 256 + tid;
  sm[tid] = (i < n) ? cnt[i] : 0;
  __syncthreads();
  for (int off = 1; off < 256; off <<= 1) {
    int t = (tid >= off) ? sm[tid - off] : 0;
    __syncthreads();
    sm[tid] += t;
    __syncthreads();
  }
  if (i < n) row_ptr[i + 1] = sm[tid] + bpre[blockIdx.x];
  if (i == 0) row_ptr[0] = 0;
}

__global__ void copy_i32(const int* __restrict__ src, int* __restrict__ dst, int n) {
  int i = blockIdx.x * blockDim.x + threadIdx.x;
  if (i < n) dst[i] = src[i];
}

// packed edge scatter: one 8B store per edge (halves write-allocate lines vs 2x4B)
__global__ void scatter_kernel(const int* __restrict__ rows, const int* __restrict__ cols,
                               const float* __restrict__ vals, int* __restrict__ fill,
                               int2* __restrict__ pk, int nnz) {
  int i = blockIdx.x * blockDim.x + threadIdx.x;
  if (i < nnz) {
    int r = rows[i];
    int pos = atomicAdd(&fill[r], 1);
    pk[pos] = make_int2(cols[i], __float_as_int(vals[i]));
  }
}

__global__ void f32_to_f16(const float* __restrict__ src, __half* __restrict__ dst, int n4) {
  int i = blockIdx.x * blockDim.x + threadIdx.x;
  if (i < n4) {
    float4 v = ((const float4*)src)[i];
    __half2* d = (__half2*)dst + 2 * (size_t)i;
    d[0] = __floats2half2_rn(v.x, v.y);
    d[1] = __floats2half2_rn(v.z, v.w);
  }
}

// b_{M-1} = c_{M-1} * X (elementwise, fp16)
__global__ void clen_first(const __half2* __restrict__ Xh, __half2* __restrict__ b,
                           const float* __restrict__ coeffs, int kidx, int n2) {
  int i = blockIdx.x * blockDim.x + threadIdx.x;
  if (i < n2) {
    const float c = coeffs[kidx];
    float2 x = __half22float2(Xh[i]);
    b[i] = __floats2half2_rn(c * x.x, c * x.y);
  }
}

// ---------------- wide gather ----------------
// Wave = 1 row. sub = lane>>4 picks 1 of 4 edges; fl = lane&15 picks an 8-feature
// quad (uint4 = 16B). One load instruction covers 4 edges x 256B = 1024B.

__device__ __forceinline__ void fma_edge(const __half* __restrict__ T, int c, float v,
                                         int fl, float2 acc[4]) {
  uint4 raw = ((const uint4*)(T + (size_t)c * FD))[fl];
  const __half2* h = (const __half2*)&raw;
  float2 x0 = __half22float2(h[0]);
  float2 x1 = __half22float2(h[1]);
  float2 x2 = __half22float2(h[2]);
  float2 x3 = __half22float2(h[3]);
  acc[0].x = fmaf(v, x0.x, acc[0].x); acc[0].y = fmaf(v, x0.y, acc[0].y);
  acc[1].x = fmaf(v, x1.x, acc[1].x); acc[1].y = fmaf(v, x1.y, acc[1].y);
  acc[2].x = fmaf(v, x2.x, acc[2].x); acc[2].y = fmaf(v, x2.y, acc[2].y);
  acc[3].x = fmaf(v, x3.x, acc[3].x); acc[3].y = fmaf(v, x3.y, acc[3].y);
}

__device__ __forceinline__ void gather_row(const int* __restrict__ rp,
                                           const int2* __restrict__ pk,
                                           const __half* __restrict__ T,
                                           int r, int sub, int fl, float2 acc[4]) {
  int e = rp[r];
  const int end = rp[r + 1];
  for (; e + 8 <= end; e += 8) {
    int2 cv0 = pk[e + sub];
    int2 cv1 = pk[e + 4 + sub];
    fma_edge(T, cv0.x, __int_as_float(cv0.y), fl, acc);
    fma_edge(T, cv1.x, __int_as_float(cv1.y), fl, acc);
  }
  if (e + 4 <= end) {
    int2 cv = pk[e + sub];
    fma_edge(T, cv.x, __int_as_float(cv.y), fl, acc);
    e += 4;
  }
  if (e < end) {
    int idx = e + sub;
    int2 cv = pk[min(idx, end - 1)];
    float v = (idx < end) ? __int_as_float(cv.y) : 0.f;
    fma_edge(T, cv.x, v, fl, acc);
  }
}

__device__ __forceinline__ void reduce_subs(float2 acc[4]) {
#pragma unroll
  for (int m = 16; m < 64; m <<= 1) {
#pragma unroll
    for (int q = 0; q < 4; ++q) {
      acc[q].x += __shfl_xor(acc[q].x, m, 64);
      acc[q].y += __shfl_xor(acc[q].y, m, 64);
    }
  }
}

// ---------------- Clenshaw steps ----------------
// b_k = 2*(L @ b_{k+1}) - b_{k+2} + c_k * X   (fp16 state, fp32 math)
// pd holds b_{k+2} and receives b_k (same element, same lane -> safe in-place).

__global__ __launch_bounds__(256) void clen_step(
    const int* __restrict__ rp, const int2* __restrict__ pk,
    const __half* __restrict__ src, const __half* __restrict__ Xh, __half* pd,
    const float* __restrict__ coeffs, int k, int has_p, int n) {
  const int lane = threadIdx.x & 63;
  const int sub = lane >> 4, fl = lane & 15;
  const int r = blockIdx.x * RPB + (threadIdx.x >> 6);
  if (r >= n) return;
  float2 acc[4] = {{0.f,0.f},{0.f,0.f},{0.f,0.f},{0.f,0.f}};
  gather_row(rp, pk, src, r, sub, fl, acc);
  reduce_subs(acc);
  if (sub == 0) {
    const float ck = coeffs[k];
    uint4 xr = ((const uint4*)(Xh + (size_t)r * FD))[fl];
    const __half2* xh = (const __half2*)&xr;
    float2 p[4] = {{0.f,0.f},{0.f,0.f},{0.f,0.f},{0.f,0.f}};
    if (has_p) {
      uint4 pr = ((const uint4*)(pd + (size_t)r * FD))[fl];
      const __half2* ph = (const __half2*)&pr;
#pragma unroll
      for (int q = 0; q < 4; ++q) p[q] = __half22float2(ph[q]);
    }
    uint4 orr;
    __half2* oh = (__half2*)&orr;
#pragma unroll
    for (int q = 0; q < 4; ++q) {
      float2 x = __half22float2(xh[q]);
      float tx = fmaf(2.f, acc[q].x, fmaf(ck, x.x, -p[q].x));
      float ty = fmaf(2.f, acc[q].y, fmaf(ck, x.y, -p[q].y));
      oh[q] = __floats2half2_rn(tx, ty);
    }
    ((uint4*)(pd + (size_t)r * FD))[fl] = orr;
  }
}

// out = c0*X + L @ b1 - b2   (fp32 X and output)
__global__ __launch_bounds__(256) void clen_final(
    const int* __restrict__ rp, const int2* __restrict__ pk,
    const __half* __restrict__ b1, const __half* __restrict__ b2,
    const float* __restrict__ X, float* __restrict__ out,
    const float* __restrict__ coeffs, int n) {
  const int lane = threadIdx.x & 63;
  const int sub = lane >> 4, fl = lane & 15;
  const int r = blockIdx.x * RPB + (threadIdx.x >> 6);
  if (r >= n) return;
  float2 acc[4] = {{0.f,0.f},{0.f,0.f},{0.f,0.f},{0.f,0.f}};
  gather_row(rp, pk, b1, r, sub, fl, acc);
  reduce_subs(acc);
  if (sub == 0) {
    const float c0 = coeffs[0];
    uint4 pr = ((const uint4*)(b2 + (size_t)r * FD))[fl];
    const __half2* ph = (const __half2*)&pr;
    float4 x0 = ((const float4*)(X + (size_t)r * FD))[fl * 2];
    float4 x1 = ((const float4*)(X + (size_t)r * FD))[fl * 2 + 1];
    float2 p0 = __half22float2(ph[0]), p1 = __half22float2(ph[1]);
    float2 p2 = __half22float2(ph[2]), p3 = __half22float2(ph[3]);
    float4 o0, o1;
    o0.x = fmaf(c0, x0.x, acc[0].x - p0.x);
    o0.y = fmaf(c0, x0.y, acc[0].y - p0.y);
    o0.z = fmaf(c0, x0.z, acc[1].x - p1.x);
    o0.w = fmaf(c0, x0.w, acc[1].y - p1.y);
    o1.x = fmaf(c0, x1.x, acc[2].x - p2.x);
    o1.y = fmaf(c0, x1.y, acc[2].y - p2.y);
    o1.z = fmaf(c0, x1.z, acc[3].x - p3.x);
    o1.w = fmaf(c0, x1.w, acc[3].y - p3.y);
    ((float4*)(out + (size_t)r * FD))[fl * 2] = o0;
    ((float4*)(out + (size_t)r * FD))[fl * 2 + 1] = o1;
  }
}

// ---------------- launch ----------------

extern "C" void kernel_launch(void* const* d_in, const int* in_sizes, int n_in,
                              void* d_out, int out_size, void* d_ws, size_t ws_size,
                              hipStream_t stream) {
  const int* rows = (const int*)d_in[0];
  const int* cols = (const int*)d_in[1];
  const float* vals = (const float*)d_in[2];
  const float* X = (const float*)d_in[3];
  const float* coeffs = (const float*)d_in[4];
  float* out = (float*)d_out;

  const int nnz = in_sizes[0];
  const int n = in_sizes[3] / FD;
  const int M = in_sizes[4];

  auto align_up = [](size_t x) { return (x + 255) & ~(size_t)255; };
  char* w = (char*)d_ws;
  size_t off = 0;
  int* row_ptr = (int*)(w + off); off = align_up(off + (size_t)(n + 1) * 4);
  int* row_fill = (int*)(w + off); off = align_up(off + (size_t)n * 4);
  int* bsum = (int*)(w + off); off = align_up(off + 1024 * 4);
  int* bpre = (int*)(w + off); off = align_up(off + 1024 * 4);
  int2* pk = (int2*)(w + off); off = align_up(off + (size_t)nnz * 8);
  __half* Xh = (__half*)(w + off); off = align_up(off + (size_t)n * FD * 2);
  __half* buf0 = (__half*)(w + off); off = align_up(off + (size_t)n * FD * 2);
  __half* buf1 = (__half*)(w + off); off = align_up(off + (size_t)n * FD * 2);
  __half* bufs[2] = {buf0, buf1};
  (void)ws_size;

  const int B = 256;
  const int gN = (n + B - 1) / B;
  const int gE = (nnz + B - 1) / B;
  const int gS = (n + RPB - 1) / RPB;
  const int n4 = n * FD / 4;
  const int gC = (n4 + B - 1) / B;
  const int n2 = n * FD / 2;
  const int gH = (n2 + B - 1) / B;

  // CSR build
  zero_i32<<<gN, B, 0, stream>>>(row_fill, n);
  hist_kernel<<<gE, B, 0, stream>>>(rows, row_fill, nnz);
  block_reduce<<<gN, B, 0, stream>>>(row_fill, bsum, n);
  scan_bsum<<<1, 1024, 0, stream>>>(bsum, bpre, gN);
  block_scan<<<gN, B, 0, stream>>>(row_fill, bpre, row_ptr, n);
  copy_i32<<<gN, B, 0, stream>>>(row_ptr, row_fill, n);
  scatter_kernel<<<gE, B, 0, stream>>>(rows, cols, vals, row_fill, pk, nnz);
  f32_to_f16<<<gC, B, 0, stream>>>(X, Xh, n4);

  // Clenshaw: b_{M-1} = c_{M-1} X ; b_k = 2 L b_{k+1} - b_{k+2} + c_k X (k = M-2..1)
  // out = c0 X + L b1 - b2.  b_j lives in bufs[j & 1]; in-place b_k over b_{k+2}.
  clen_first<<<gH, B, 0, stream>>>((const __half2*)Xh, (__half2*)bufs[(M - 1) & 1],
                                   coeffs, M - 1, n2);
  for (int k = M - 2; k >= 1; --k) {
    clen_step<<<gS, B, 0, stream>>>(row_ptr, pk, bufs[(k + 1) & 1], Xh, bufs[k & 1],
                                    coeffs, k, (k < M - 2) ? 1 : 0, n);
  }
  clen_final<<<gS, B, 0, stream>>>(row_ptr, pk, bufs[1], bufs[0], X, out, coeffs, n);
}